// Round 13
// baseline (238.106 us; speedup 1.0000x reference)
//
#include <hip/hip_runtime.h>
#include <hip/hip_fp8.h>

#define N_NODES 50000
#define N_EDGES 800000
#define D_IN 128
#define HIDDEN 128
#define N_CLASSES 40

#define M_PAD 50048      // 782 * 64
#define CAP 64           // bucket capacity per node (deg ~ Binom(800k,1/50k))
#define EDGE_BATCH_BLOCKS 391  // 391*256*8 = 800768 >= 800000

typedef __attribute__((ext_vector_type(8))) short short8;
typedef __attribute__((ext_vector_type(4))) float floatx4;

static __device__ __forceinline__ unsigned short f2bf(float f) {
    unsigned u = __float_as_uint(f);
    u = (u + 0x7fffu + ((u >> 16) & 1u)) >> 16;  // RNE
    return (unsigned short)u;
}
static __device__ __forceinline__ float bf2f(unsigned short b) {
    return __uint_as_float(((unsigned)b) << 16);
}
// fp8 e4m3 (OCP, gfx950) encode/decode via HIP type (HW cvt on gfx950)
static __device__ __forceinline__ unsigned char f2fp8(float v) {
    __hip_fp8_e4m3 t(v);
    return (unsigned char)t.__x;
}
static __device__ __forceinline__ float fp82f(unsigned char b) {
    __hip_fp8_e4m3 t;
    t.__x = (__hip_fp8_storage_t)b;
    return (float)t;
}

// ---------------------------------------------------------------------------
// prep: W1 -> transposed bf16, W2 -> transposed bf16, cnt -> 0.
// ---------------------------------------------------------------------------
#define KP_W1 128                      // 32768 elems / 256
#define KP_W2 40                       // 10240 elems / 256
#define KP_CNT 196                     // 50000 ints / 256
#define KP_GRID (KP_W1 + KP_W2 + KP_CNT)

__global__ __launch_bounds__(256) void prep_kernel(
    const float* __restrict__ W1l, const float* __restrict__ W1r,
    unsigned short* __restrict__ Wt1, const float* __restrict__ W2l,
    const float* __restrict__ W2r, unsigned short* __restrict__ Wt2,
    int* __restrict__ cnt) {
    int b = blockIdx.x;
    int t = threadIdx.x;
    if (b < KP_W1) {
        int i = b * 256 + t;  // < 256*128
        int n = i >> 7, k = i & 127;
        float v = (n < 128) ? W1l[k * 128 + n] : W1r[k * 128 + (n - 128)];
        Wt1[n * 128 + k] = f2bf(v);
    } else if (b < KP_W1 + KP_W2) {
        int i = (b - KP_W1) * 256 + t;  // < 80*128
        int n = i >> 7, k = i & 127;
        float v = (n < 40) ? W2l[k * 40 + n] : W2r[k * 40 + (n - 40)];
        Wt2[n * 128 + k] = f2bf(v);
    } else {
        int i = (b - KP_W1 - KP_W2) * 256 + t;
        if (i < N_NODES) cnt[i] = 0;
    }
}

// ---------------------------------------------------------------------------
// SINGLE-PASS adjacency build: fixed-capacity USHORT buckets, ONE atomic per
// edge. ~45 us is the measured 800k-random-RMW HW floor (r6/r8/r9/r10/r11
// invariant — insensitive to ILP, striping, entry width). Do not add passes.
// Overflow (p >= CAP) is statistically impossible (P(deg>64) ~ e-20) and
// degrades to a dropped edge, not UB.
// ---------------------------------------------------------------------------
__global__ __launch_bounds__(256) void fill_bucket_kernel(
    const int* __restrict__ src, const int* __restrict__ dst,
    int* __restrict__ cnt, unsigned short* __restrict__ bucket) {
    int i0 = (blockIdx.x * 256 + threadIdx.x) * 8;
    if (i0 >= N_EDGES) return;  // 800000 % 8 == 0 -> full groups only
    int4 d0 = *(const int4*)(dst + i0);
    int4 d1 = *(const int4*)(dst + i0 + 4);
    int4 s0 = *(const int4*)(src + i0);
    int4 s1 = *(const int4*)(src + i0 + 4);
    int p0 = atomicAdd(&cnt[d0.x], 1);
    int p1 = atomicAdd(&cnt[d0.y], 1);
    int p2 = atomicAdd(&cnt[d0.z], 1);
    int p3 = atomicAdd(&cnt[d0.w], 1);
    int p4 = atomicAdd(&cnt[d1.x], 1);
    int p5 = atomicAdd(&cnt[d1.y], 1);
    int p6 = atomicAdd(&cnt[d1.z], 1);
    int p7 = atomicAdd(&cnt[d1.w], 1);
    if (p0 < CAP) bucket[d0.x * CAP + p0] = (unsigned short)s0.x;
    if (p1 < CAP) bucket[d0.y * CAP + p1] = (unsigned short)s0.y;
    if (p2 < CAP) bucket[d0.z * CAP + p2] = (unsigned short)s0.z;
    if (p3 < CAP) bucket[d0.w * CAP + p3] = (unsigned short)s0.w;
    if (p4 < CAP) bucket[d1.x * CAP + p4] = (unsigned short)s1.x;
    if (p5 < CAP) bucket[d1.y * CAP + p5] = (unsigned short)s1.y;
    if (p6 < CAP) bucket[d1.z * CAP + p6] = (unsigned short)s1.z;
    if (p7 < CAP) bucket[d1.w * CAP + p7] = (unsigned short)s1.w;
}

// ---------------------------------------------------------------------------
// MFMA GEMM layer 1 with LDS-staged A (r11 win): block loads its 64x128 fp32
// x-tile ONCE, converts to bf16 into LDS; all 4 waves read frags from LDS.
// Outputs: cols 0..127 -> ylb as FP8 e4m3 (gathered 16x — fp8 halves the
// MALL gather, r12 win), cols 128..255 -> yrb bf16 (read once).
// Row pad +8 bf16 -> 2-way LDS bank aliasing only (free, m136).
// Wave layout (m89/m120-verified): A[m=lane&15][k=quad*8+j],
// B[k=quad*8+j][n=lane&15], D col=lane&15, row=quad*4+reg.
// ---------------------------------------------------------------------------
#define A_LD 136  // 128 + 8 pad (ushort units); row stride 272 B (16B-mult)

__global__ __launch_bounds__(256) void gemm1_mfma_kernel(
    const float* __restrict__ x, const unsigned short* __restrict__ Wt,
    unsigned char* __restrict__ ylb, unsigned short* __restrict__ yrb) {
    __shared__ unsigned short sA[64][A_LD];  // 17408 B

    const int wave = threadIdx.x >> 6;
    const int lane = threadIdx.x & 63;
    const int r = lane & 15, q = lane >> 4;
    const int m0 = blockIdx.x * 64;
    const int n0 = wave * 64;
    const int t = threadIdx.x;

    // Stage + convert: 64 rows x 32 float4-groups = 2048 loads, 8/thread.
#pragma unroll
    for (int i = 0; i < 8; i++) {
        int g = t + i * 256;
        int row = g >> 5;             // 0..63
        int k4 = (g & 31) << 2;       // 0,4,...,124
        int gr = m0 + row;
        if (gr >= N_NODES) gr = N_NODES - 1;
        float4 v = *(const float4*)(x + (size_t)gr * 128 + k4);
        uint2 p;
        p.x = (unsigned)f2bf(v.x) | ((unsigned)f2bf(v.y) << 16);
        p.y = (unsigned)f2bf(v.z) | ((unsigned)f2bf(v.w) << 16);
        *(uint2*)&sA[row][k4] = p;
    }
    __syncthreads();

    floatx4 acc[4][4];
#pragma unroll
    for (int i = 0; i < 4; i++)
#pragma unroll
        for (int j = 0; j < 4; j++) acc[i][j] = (floatx4){0.f, 0.f, 0.f, 0.f};

#pragma unroll
    for (int kc = 0; kc < 128; kc += 32) {
        short8 a[4], bb[4];
#pragma unroll
        for (int mi = 0; mi < 4; mi++)
            a[mi] = *(const short8*)&sA[mi * 16 + r][kc + q * 8];
#pragma unroll
        for (int ni = 0; ni < 4; ni++)
            bb[ni] = *(const short8*)(Wt + (size_t)(n0 + ni * 16 + r) * 128 + kc + q * 8);
#pragma unroll
        for (int mi = 0; mi < 4; mi++)
#pragma unroll
            for (int ni = 0; ni < 4; ni++)
                acc[mi][ni] = __builtin_amdgcn_mfma_f32_16x16x32_bf16(
                    a[mi], bb[ni], acc[mi][ni], 0, 0, 0);
    }

#pragma unroll
    for (int mi = 0; mi < 4; mi++) {
        int rowb = m0 + mi * 16 + q * 4;
#pragma unroll
        for (int ni = 0; ni < 4; ni++) {
            int col = n0 + ni * 16 + r;
#pragma unroll
            for (int reg = 0; reg < 4; reg++) {
                int gr = rowb + reg;
                if (gr < N_NODES) {
                    float v = acc[mi][ni][reg];
                    if (col < 128)
                        ylb[(size_t)gr * 128 + col] = f2fp8(v);
                    else
                        yrb[(size_t)gr * 128 + (col - 128)] = f2bf(v);
                }
            }
        }
    }
}

// ---------------------------------------------------------------------------
// FUSED agg_relu1 + gemm2 (r13): block = 64 nodes, 4 waves.
// Phase 1: wave w aggregates nodes {w, w+4, ..., w+60} (fp8 gather, 8-deep
//   unroll), epilogue h = relu(mean+yr+b1), h written as bf16 into LDS
//   (NEVER materialized to global — kills hb's 25.6 MB round-trip).
// Phase 2: gemm2 on sH: [64x128 bf16] @ [Wt2 80x128] -> zlb/zrb bf16.
// sH pad +8 (row stride 272 B, 16B multiple) — same recipe as gemm1's sA.
// h rounding point identical to r12 (bf16 RNE) -> bit-identical numerics.
// ---------------------------------------------------------------------------
__global__ __launch_bounds__(256) void agg1_gemm2_kernel(
    const unsigned short* __restrict__ yl8, const int* __restrict__ cnt,
    const unsigned short* __restrict__ bucket, const float2* __restrict__ b12,
    const unsigned int* __restrict__ yru, const unsigned short* __restrict__ Wt,
    unsigned short* __restrict__ zlb, unsigned short* __restrict__ zrb) {
    __shared__ unsigned short sH[64][A_LD];  // 17408 B

    const int wave = threadIdx.x >> 6;
    const int lane = threadIdx.x & 63;
    const int m0 = blockIdx.x * 64;

    // ---- Phase 1: aggregate 16 nodes per wave ----
    float2 b = b12[lane];
#pragma unroll 1
    for (int i = 0; i < 16; i++) {
        int row = wave + i * 4;  // waves interleave rows 0..63
        int n = m0 + row;
        float ox = 0.f, oy = 0.f;
        if (n < N_NODES) {
            int deg = cnt[n];
            int re = min(deg, CAP);
            const unsigned short* bk = bucket + n * CAP;
            float ax = 0.f, ay = 0.f, bx = 0.f, by = 0.f;
            int e = 0;
            for (; e + 7 < re; e += 8) {
                unsigned short u[8];
#pragma unroll
                for (int j = 0; j < 8; j++) {
                    int s = bk[e + j];
                    u[j] = yl8[(size_t)s * 64 + lane];
                }
#pragma unroll
                for (int j = 0; j < 8; j += 2) {
                    ax += fp82f(u[j] & 0xff); ay += fp82f(u[j] >> 8);
                    bx += fp82f(u[j + 1] & 0xff); by += fp82f(u[j + 1] >> 8);
                }
            }
            for (; e + 3 < re; e += 4) {
                int s0 = bk[e + 0], s1 = bk[e + 1], s2 = bk[e + 2], s3 = bk[e + 3];
                unsigned short u0 = yl8[(size_t)s0 * 64 + lane];
                unsigned short u1 = yl8[(size_t)s1 * 64 + lane];
                unsigned short u2 = yl8[(size_t)s2 * 64 + lane];
                unsigned short u3 = yl8[(size_t)s3 * 64 + lane];
                ax += fp82f(u0 & 0xff); ay += fp82f(u0 >> 8);
                bx += fp82f(u1 & 0xff); by += fp82f(u1 >> 8);
                ax += fp82f(u2 & 0xff); ay += fp82f(u2 >> 8);
                bx += fp82f(u3 & 0xff); by += fp82f(u3 >> 8);
            }
            for (; e < re; e++) {
                unsigned short u0 = yl8[(size_t)bk[e] * 64 + lane];
                ax += fp82f(u0 & 0xff); ay += fp82f(u0 >> 8);
            }
            float inv = 1.0f / (float)max(deg, 1);
            unsigned ur = yru[(size_t)n * 64 + lane];
            ox = fmaxf((ax + bx) * inv + bf2f(ur & 0xffff) + b.x, 0.0f);
            oy = fmaxf((ay + by) * inv + bf2f(ur >> 16) + b.y, 0.0f);
        }
        // lane l writes cols 2l,2l+1 -> 4B store, bank = lane%32 (2-way, free)
        unsigned pk = (unsigned)f2bf(ox) | ((unsigned)f2bf(oy) << 16);
        *(unsigned*)&sH[row][2 * lane] = pk;
    }
    __syncthreads();

    // ---- Phase 2: gemm2 from LDS ----
    const int r = lane & 15, q = lane >> 4;
    const int rl = wave * 16;  // local row base of this wave

    floatx4 acc[5];
#pragma unroll
    for (int i = 0; i < 5; i++) acc[i] = (floatx4){0.f, 0.f, 0.f, 0.f};

#pragma unroll
    for (int kc = 0; kc < 128; kc += 32) {
        short8 a = *(const short8*)&sH[rl + r][kc + q * 8];
        short8 bb[5];
#pragma unroll
        for (int ni = 0; ni < 5; ni++)
            bb[ni] = *(const short8*)(Wt + (size_t)(ni * 16 + r) * 128 + kc + q * 8);
#pragma unroll
        for (int ni = 0; ni < 5; ni++)
            acc[ni] = __builtin_amdgcn_mfma_f32_16x16x32_bf16(a, bb[ni], acc[ni], 0, 0, 0);
    }

    int rowb = m0 + rl + q * 4;
#pragma unroll
    for (int ni = 0; ni < 5; ni++) {
        int col = ni * 16 + r;
#pragma unroll
        for (int reg = 0; reg < 4; reg++) {
            int gr = rowb + reg;
            if (gr < N_NODES) {
                unsigned short v = f2bf(acc[ni][reg]);
                if (col < 40)
                    zlb[(size_t)gr * 40 + col] = v;
                else
                    zrb[(size_t)gr * 40 + (col - 40)] = v;
            }
        }
    }
}

// ---------------------------------------------------------------------------
// Fused agg + epilogue layer 2 (bf16 z), bucket traversal:
//   out[n][c] = (1/max(cnt,1)) * sum_j zl[bucket[n][j]][c] + zr[n][c] + b2[c]
// ---------------------------------------------------------------------------
__global__ __launch_bounds__(256) void agg_out2_kernel(
    const unsigned short* __restrict__ zlb, const unsigned short* __restrict__ zrb,
    const int* __restrict__ cnt, const unsigned short* __restrict__ bucket,
    const float* __restrict__ b2, float* __restrict__ out) {
    int n = blockIdx.x * 4 + (threadIdx.x >> 6);
    if (n >= N_NODES) return;
    int c = threadIdx.x & 63;
    if (c >= N_CLASSES) return;
    int deg = cnt[n];
    int re = min(deg, CAP);
    const unsigned short* bk = bucket + n * CAP;
    float a0 = 0.f, a1 = 0.f;
    int e = 0;
    for (; e + 3 < re; e += 4) {
        int s0 = bk[e + 0], s1 = bk[e + 1], s2 = bk[e + 2], s3 = bk[e + 3];
        float v0 = bf2f(zlb[(size_t)s0 * 40 + c]);
        float v1 = bf2f(zlb[(size_t)s1 * 40 + c]);
        float v2 = bf2f(zlb[(size_t)s2 * 40 + c]);
        float v3 = bf2f(zlb[(size_t)s3 * 40 + c]);
        a0 += v0 + v2;
        a1 += v1 + v3;
    }
    for (; e < re; e++) a0 += bf2f(zlb[(size_t)bk[e] * 40 + c]);
    float inv = 1.0f / (float)max(deg, 1);
    out[(size_t)n * 40 + c] =
        (a0 + a1) * inv + bf2f(zrb[(size_t)n * 40 + c]) + b2[c];
}

// ---------------------------------------------------------------------------
extern "C" void kernel_launch(void* const* d_in, const int* in_sizes, int n_in,
                              void* d_out, int out_size, void* d_ws, size_t ws_size,
                              hipStream_t stream) {
    const float* x   = (const float*)d_in[0];
    const int*   ei  = (const int*)d_in[1];   // [2, E]: src row then dst row
    const float* W1l = (const float*)d_in[2];
    const float* b1  = (const float*)d_in[3];
    const float* W1r = (const float*)d_in[4];
    const float* W2l = (const float*)d_in[5];
    const float* b2  = (const float*)d_in[6];
    const float* W2r = (const float*)d_in[7];
    float* out = (float*)d_out;

    const int* src = ei;
    const int* dst = ei + N_EDGES;

    // Workspace layout (bytes), strictly non-overlapping, 16B-aligned
    // (hb eliminated by the r13 fusion):
    //  cnt    @ 0            200,000   (pad to 262,144)
    //  bucket @ 262,144    6,400,000   ends  6,662,144  (ushort)
    //  Wt1    @ 6,662,144     65,536   ends  6,727,680
    //  Wt2    @ 6,727,680     20,480   ends  6,748,160
    //  ylb    @ 6,748,160   6,400,000  ends 13,148,160  (fp8 e4m3)
    //  yrb    @ 13,148,160 12,800,000  ends 25,948,160  (bf16)
    //  zlb    @ 25,948,160  4,000,000  ends 29,948,160  (bf16)
    //  zrb    @ 29,948,160  4,000,000  ends 33,948,160  (< 256 MiB)
    char* ws = (char*)d_ws;
    int* cnt               = (int*)(ws);
    unsigned short* bucket = (unsigned short*)(ws + 262144);
    unsigned short* Wt1    = (unsigned short*)(ws + 6662144);
    unsigned short* Wt2    = (unsigned short*)(ws + 6727680);
    unsigned char*  ylb    = (unsigned char*)(ws + 6748160);
    unsigned short* yrb    = (unsigned short*)(ws + 13148160);
    unsigned short* zlb    = (unsigned short*)(ws + 25948160);
    unsigned short* zrb    = (unsigned short*)(ws + 29948160);

    // --- prep (weight transposes + cnt zero) + bucket build (1 atomic pass)
    prep_kernel<<<KP_GRID, 256, 0, stream>>>(W1l, W1r, Wt1, W2l, W2r, Wt2, cnt);
    fill_bucket_kernel<<<EDGE_BATCH_BLOCKS, 256, 0, stream>>>(src, dst, cnt,
                                                              bucket);

    // --- Layer 1 GEMM (x converted inline via LDS staging; ylb fp8)
    gemm1_mfma_kernel<<<M_PAD / 64, 256, 0, stream>>>(x, Wt1, ylb, yrb);

    // --- Fused layer-1 aggregation + layer-2 GEMM (h lives in LDS only)
    agg1_gemm2_kernel<<<M_PAD / 64, 256, 0, stream>>>(
        (const unsigned short*)ylb, cnt, bucket, (const float2*)b1,
        (const unsigned int*)yrb, Wt2, zlb, zrb);

    // --- Layer 2 aggregation + output
    agg_out2_kernel<<<(N_NODES + 3) / 4, 256, 0, stream>>>(
        zlb, zrb, cnt, bucket, b2, out);
}

// Round 14
// 219.483 us; speedup vs baseline: 1.0849x; 1.0849x over previous
//
#include <hip/hip_runtime.h>
#include <hip/hip_fp8.h>

#define N_NODES 50000
#define N_EDGES 800000
#define D_IN 128
#define HIDDEN 128
#define N_CLASSES 40

#define M_PAD 50048      // 782 * 64
#define CAP 64           // bucket capacity per node (deg ~ Binom(800k,1/50k))
#define EDGE_BATCH_BLOCKS 391  // 391*256*8 = 800768 >= 800000

typedef __attribute__((ext_vector_type(8))) short short8;
typedef __attribute__((ext_vector_type(4))) float floatx4;

static __device__ __forceinline__ unsigned short f2bf(float f) {
    unsigned u = __float_as_uint(f);
    u = (u + 0x7fffu + ((u >> 16) & 1u)) >> 16;  // RNE
    return (unsigned short)u;
}
static __device__ __forceinline__ float bf2f(unsigned short b) {
    return __uint_as_float(((unsigned)b) << 16);
}
// fp8 e4m3 (OCP, gfx950) encode/decode via HIP type (HW cvt on gfx950)
static __device__ __forceinline__ unsigned char f2fp8(float v) {
    __hip_fp8_e4m3 t(v);
    return (unsigned char)t.__x;
}
static __device__ __forceinline__ float fp82f(unsigned char b) {
    __hip_fp8_e4m3 t;
    t.__x = (__hip_fp8_storage_t)b;
    return (float)t;
}

// ---------------------------------------------------------------------------
// prep: W1 -> transposed bf16, W2 -> transposed bf16, cnt -> 0.
// ---------------------------------------------------------------------------
#define KP_W1 128                      // 32768 elems / 256
#define KP_W2 40                       // 10240 elems / 256
#define KP_CNT 196                     // 50000 ints / 256
#define KP_GRID (KP_W1 + KP_W2 + KP_CNT)

__global__ __launch_bounds__(256) void prep_kernel(
    const float* __restrict__ W1l, const float* __restrict__ W1r,
    unsigned short* __restrict__ Wt1, const float* __restrict__ W2l,
    const float* __restrict__ W2r, unsigned short* __restrict__ Wt2,
    int* __restrict__ cnt) {
    int b = blockIdx.x;
    int t = threadIdx.x;
    if (b < KP_W1) {
        int i = b * 256 + t;  // < 256*128
        int n = i >> 7, k = i & 127;
        float v = (n < 128) ? W1l[k * 128 + n] : W1r[k * 128 + (n - 128)];
        Wt1[n * 128 + k] = f2bf(v);
    } else if (b < KP_W1 + KP_W2) {
        int i = (b - KP_W1) * 256 + t;  // < 80*128
        int n = i >> 7, k = i & 127;
        float v = (n < 40) ? W2l[k * 40 + n] : W2r[k * 40 + (n - 40)];
        Wt2[n * 128 + k] = f2bf(v);
    } else {
        int i = (b - KP_W1 - KP_W2) * 256 + t;
        if (i < N_NODES) cnt[i] = 0;
    }
}

// ---------------------------------------------------------------------------
// SINGLE-PASS adjacency build: fixed-capacity USHORT buckets, ONE atomic per
// edge. ~45 us is the measured 800k-random-RMW HW floor (r6/r8/r9/r10/r11
// invariant — insensitive to ILP, striping, entry width). Do not add passes.
// Overflow (p >= CAP) is statistically impossible (P(deg>64) ~ e-20) and
// degrades to a dropped edge, not UB.
// ---------------------------------------------------------------------------
__global__ __launch_bounds__(256) void fill_bucket_kernel(
    const int* __restrict__ src, const int* __restrict__ dst,
    int* __restrict__ cnt, unsigned short* __restrict__ bucket) {
    int i0 = (blockIdx.x * 256 + threadIdx.x) * 8;
    if (i0 >= N_EDGES) return;  // 800000 % 8 == 0 -> full groups only
    int4 d0 = *(const int4*)(dst + i0);
    int4 d1 = *(const int4*)(dst + i0 + 4);
    int4 s0 = *(const int4*)(src + i0);
    int4 s1 = *(const int4*)(src + i0 + 4);
    int p0 = atomicAdd(&cnt[d0.x], 1);
    int p1 = atomicAdd(&cnt[d0.y], 1);
    int p2 = atomicAdd(&cnt[d0.z], 1);
    int p3 = atomicAdd(&cnt[d0.w], 1);
    int p4 = atomicAdd(&cnt[d1.x], 1);
    int p5 = atomicAdd(&cnt[d1.y], 1);
    int p6 = atomicAdd(&cnt[d1.z], 1);
    int p7 = atomicAdd(&cnt[d1.w], 1);
    if (p0 < CAP) bucket[d0.x * CAP + p0] = (unsigned short)s0.x;
    if (p1 < CAP) bucket[d0.y * CAP + p1] = (unsigned short)s0.y;
    if (p2 < CAP) bucket[d0.z * CAP + p2] = (unsigned short)s0.z;
    if (p3 < CAP) bucket[d0.w * CAP + p3] = (unsigned short)s0.w;
    if (p4 < CAP) bucket[d1.x * CAP + p4] = (unsigned short)s1.x;
    if (p5 < CAP) bucket[d1.y * CAP + p5] = (unsigned short)s1.y;
    if (p6 < CAP) bucket[d1.z * CAP + p6] = (unsigned short)s1.z;
    if (p7 < CAP) bucket[d1.w * CAP + p7] = (unsigned short)s1.w;
}

// ---------------------------------------------------------------------------
// MFMA GEMM layer 1 with LDS-staged A (r11 win): block loads its 64x128 fp32
// x-tile ONCE, converts to bf16 into LDS; all 4 waves read frags from LDS.
// Outputs: cols 0..127 -> ylb as FP8 e4m3 (gathered 16x — fp8 halves the
// MALL gather, r12 win), cols 128..255 -> yrb bf16 (read once).
// Row pad +8 bf16 -> 2-way LDS bank aliasing only (free, m136).
// Wave layout (m89/m120-verified): A[m=lane&15][k=quad*8+j],
// B[k=quad*8+j][n=lane&15], D col=lane&15, row=quad*4+reg.
// ---------------------------------------------------------------------------
#define A_LD 136  // 128 + 8 pad (ushort units); row stride 272 B (16B-mult)

__global__ __launch_bounds__(256) void gemm1_mfma_kernel(
    const float* __restrict__ x, const unsigned short* __restrict__ Wt,
    unsigned char* __restrict__ ylb, unsigned short* __restrict__ yrb) {
    __shared__ unsigned short sA[64][A_LD];  // 17408 B

    const int wave = threadIdx.x >> 6;
    const int lane = threadIdx.x & 63;
    const int r = lane & 15, q = lane >> 4;
    const int m0 = blockIdx.x * 64;
    const int n0 = wave * 64;
    const int t = threadIdx.x;

    // Stage + convert: 64 rows x 32 float4-groups = 2048 loads, 8/thread.
#pragma unroll
    for (int i = 0; i < 8; i++) {
        int g = t + i * 256;
        int row = g >> 5;             // 0..63
        int k4 = (g & 31) << 2;       // 0,4,...,124
        int gr = m0 + row;
        if (gr >= N_NODES) gr = N_NODES - 1;
        float4 v = *(const float4*)(x + (size_t)gr * 128 + k4);
        uint2 p;
        p.x = (unsigned)f2bf(v.x) | ((unsigned)f2bf(v.y) << 16);
        p.y = (unsigned)f2bf(v.z) | ((unsigned)f2bf(v.w) << 16);
        *(uint2*)&sA[row][k4] = p;
    }
    __syncthreads();

    floatx4 acc[4][4];
#pragma unroll
    for (int i = 0; i < 4; i++)
#pragma unroll
        for (int j = 0; j < 4; j++) acc[i][j] = (floatx4){0.f, 0.f, 0.f, 0.f};

#pragma unroll
    for (int kc = 0; kc < 128; kc += 32) {
        short8 a[4], bb[4];
#pragma unroll
        for (int mi = 0; mi < 4; mi++)
            a[mi] = *(const short8*)&sA[mi * 16 + r][kc + q * 8];
#pragma unroll
        for (int ni = 0; ni < 4; ni++)
            bb[ni] = *(const short8*)(Wt + (size_t)(n0 + ni * 16 + r) * 128 + kc + q * 8);
#pragma unroll
        for (int mi = 0; mi < 4; mi++)
#pragma unroll
            for (int ni = 0; ni < 4; ni++)
                acc[mi][ni] = __builtin_amdgcn_mfma_f32_16x16x32_bf16(
                    a[mi], bb[ni], acc[mi][ni], 0, 0, 0);
    }

#pragma unroll
    for (int mi = 0; mi < 4; mi++) {
        int rowb = m0 + mi * 16 + q * 4;
#pragma unroll
        for (int ni = 0; ni < 4; ni++) {
            int col = n0 + ni * 16 + r;
#pragma unroll
            for (int reg = 0; reg < 4; reg++) {
                int gr = rowb + reg;
                if (gr < N_NODES) {
                    float v = acc[mi][ni][reg];
                    if (col < 128)
                        ylb[(size_t)gr * 128 + col] = f2fp8(v);
                    else
                        yrb[(size_t)gr * 128 + (col - 128)] = f2bf(v);
                }
            }
        }
    }
}

// ---------------------------------------------------------------------------
// MFMA GEMM layer 2 (separate — r13 fusion with agg_relu1 regressed 218->238:
// tile-shaped fusion cut gather wave-parallelism 50k->3k): [hb 50048x128
// bf16] @ [Wt2 80x128 bf16] -> cols 0..39 -> zlb bf16, cols 40..79 -> zrb.
// ---------------------------------------------------------------------------
__global__ __launch_bounds__(256) void gemm2_mfma_kernel(
    const unsigned short* __restrict__ hb, const unsigned short* __restrict__ Wt,
    unsigned short* __restrict__ zlb, unsigned short* __restrict__ zrb) {
    const int wave = threadIdx.x >> 6;
    const int lane = threadIdx.x & 63;
    const int r = lane & 15, q = lane >> 4;
    const int m0 = blockIdx.x * 64 + wave * 16;

    floatx4 acc[5];
#pragma unroll
    for (int i = 0; i < 5; i++) acc[i] = (floatx4){0.f, 0.f, 0.f, 0.f};

#pragma unroll
    for (int kc = 0; kc < 128; kc += 32) {
        short8 a = *(const short8*)(hb + (size_t)(m0 + r) * 128 + kc + q * 8);
        short8 b[5];
#pragma unroll
        for (int ni = 0; ni < 5; ni++)
            b[ni] = *(const short8*)(Wt + (size_t)(ni * 16 + r) * 128 + kc + q * 8);
#pragma unroll
        for (int ni = 0; ni < 5; ni++)
            acc[ni] = __builtin_amdgcn_mfma_f32_16x16x32_bf16(a, b[ni], acc[ni], 0, 0, 0);
    }

    int rowb = m0 + q * 4;
#pragma unroll
    for (int ni = 0; ni < 5; ni++) {
        int col = ni * 16 + r;
#pragma unroll
        for (int reg = 0; reg < 4; reg++) {
            int gr = rowb + reg;
            if (gr < N_NODES) {
                unsigned short v = f2bf(acc[ni][reg]);
                if (col < 40)
                    zlb[(size_t)gr * 40 + col] = v;
                else
                    zrb[(size_t)gr * 40 + (col - 40)] = v;
            }
        }
    }
}

// ---------------------------------------------------------------------------
// Fused agg + epilogue layer 1, FP8 gather (128 B/row), 8-deep unroll.
// ONE NODE PER WAVE (50k waves — gather throughput comes from wave count;
// r13's 16-nodes-per-wave fusion proved this the hard way):
//   h[n] = relu( (1/max(cnt,1)) * sum_j yl[bucket[n][j]] + yr[n] + b1 )
// ---------------------------------------------------------------------------
__global__ __launch_bounds__(256) void agg_relu1_kernel(
    const unsigned short* __restrict__ yl8, const int* __restrict__ cnt,
    const unsigned short* __restrict__ bucket, const float2* __restrict__ b12,
    const unsigned int* __restrict__ yru, unsigned int* __restrict__ hbu) {
    int n = blockIdx.x * 4 + (threadIdx.x >> 6);
    if (n >= N_NODES) return;
    int l = threadIdx.x & 63;
    int deg = cnt[n];
    int re = min(deg, CAP);
    const unsigned short* bk = bucket + n * CAP;
    float ax = 0.f, ay = 0.f, bx = 0.f, by = 0.f;
    int e = 0;
    for (; e + 7 < re; e += 8) {
        unsigned short u[8];
#pragma unroll
        for (int j = 0; j < 8; j++) {
            int s = bk[e + j];
            u[j] = yl8[(size_t)s * 64 + l];
        }
#pragma unroll
        for (int j = 0; j < 8; j += 2) {
            ax += fp82f(u[j] & 0xff); ay += fp82f(u[j] >> 8);
            bx += fp82f(u[j + 1] & 0xff); by += fp82f(u[j + 1] >> 8);
        }
    }
    for (; e + 3 < re; e += 4) {
        int s0 = bk[e + 0], s1 = bk[e + 1], s2 = bk[e + 2], s3 = bk[e + 3];
        unsigned short u0 = yl8[(size_t)s0 * 64 + l];
        unsigned short u1 = yl8[(size_t)s1 * 64 + l];
        unsigned short u2 = yl8[(size_t)s2 * 64 + l];
        unsigned short u3 = yl8[(size_t)s3 * 64 + l];
        ax += fp82f(u0 & 0xff); ay += fp82f(u0 >> 8);
        bx += fp82f(u1 & 0xff); by += fp82f(u1 >> 8);
        ax += fp82f(u2 & 0xff); ay += fp82f(u2 >> 8);
        bx += fp82f(u3 & 0xff); by += fp82f(u3 >> 8);
    }
    for (; e < re; e++) {
        unsigned short u0 = yl8[(size_t)bk[e] * 64 + l];
        ax += fp82f(u0 & 0xff); ay += fp82f(u0 >> 8);
    }
    float inv = 1.0f / (float)max(deg, 1);
    unsigned ur = yru[(size_t)n * 64 + l];
    float2 b = b12[l];
    float ox = fmaxf((ax + bx) * inv + bf2f(ur & 0xffff) + b.x, 0.0f);
    float oy = fmaxf((ay + by) * inv + bf2f(ur >> 16) + b.y, 0.0f);
    hbu[(size_t)n * 64 + l] = (unsigned)f2bf(ox) | ((unsigned)f2bf(oy) << 16);
}

// ---------------------------------------------------------------------------
// Fused agg + epilogue layer 2 (bf16 z), bucket traversal:
//   out[n][c] = (1/max(cnt,1)) * sum_j zl[bucket[n][j]][c] + zr[n][c] + b2[c]
// ---------------------------------------------------------------------------
__global__ __launch_bounds__(256) void agg_out2_kernel(
    const unsigned short* __restrict__ zlb, const unsigned short* __restrict__ zrb,
    const int* __restrict__ cnt, const unsigned short* __restrict__ bucket,
    const float* __restrict__ b2, float* __restrict__ out) {
    int n = blockIdx.x * 4 + (threadIdx.x >> 6);
    if (n >= N_NODES) return;
    int c = threadIdx.x & 63;
    if (c >= N_CLASSES) return;
    int deg = cnt[n];
    int re = min(deg, CAP);
    const unsigned short* bk = bucket + n * CAP;
    float a0 = 0.f, a1 = 0.f;
    int e = 0;
    for (; e + 3 < re; e += 4) {
        int s0 = bk[e + 0], s1 = bk[e + 1], s2 = bk[e + 2], s3 = bk[e + 3];
        float v0 = bf2f(zlb[(size_t)s0 * 40 + c]);
        float v1 = bf2f(zlb[(size_t)s1 * 40 + c]);
        float v2 = bf2f(zlb[(size_t)s2 * 40 + c]);
        float v3 = bf2f(zlb[(size_t)s3 * 40 + c]);
        a0 += v0 + v2;
        a1 += v1 + v3;
    }
    for (; e < re; e++) a0 += bf2f(zlb[(size_t)bk[e] * 40 + c]);
    float inv = 1.0f / (float)max(deg, 1);
    out[(size_t)n * 40 + c] =
        (a0 + a1) * inv + bf2f(zrb[(size_t)n * 40 + c]) + b2[c];
}

// ---------------------------------------------------------------------------
extern "C" void kernel_launch(void* const* d_in, const int* in_sizes, int n_in,
                              void* d_out, int out_size, void* d_ws, size_t ws_size,
                              hipStream_t stream) {
    const float* x   = (const float*)d_in[0];
    const int*   ei  = (const int*)d_in[1];   // [2, E]: src row then dst row
    const float* W1l = (const float*)d_in[2];
    const float* b1  = (const float*)d_in[3];
    const float* W1r = (const float*)d_in[4];
    const float* W2l = (const float*)d_in[5];
    const float* b2  = (const float*)d_in[6];
    const float* W2r = (const float*)d_in[7];
    float* out = (float*)d_out;

    const int* src = ei;
    const int* dst = ei + N_EDGES;

    // Workspace layout (bytes), strictly non-overlapping, 16B-aligned
    // (identical to r12 — the 218 us configuration):
    //  cnt    @ 0            200,000   (pad to 262,144)
    //  bucket @ 262,144    6,400,000   ends  6,662,144  (ushort)
    //  Wt1    @ 6,662,144     65,536   ends  6,727,680
    //  Wt2    @ 6,727,680     20,480   ends  6,748,160
    //  hb     @ 6,748,160  12,812,288  ends 19,560,448  (M_PAD rows, bf16)
    //  ylb    @ 19,560,448  6,400,000  ends 25,960,448  (fp8 e4m3)
    //  yrb    @ 25,960,448 12,800,000  ends 38,760,448  (bf16)
    //  zlb    @ 38,760,448  4,000,000  ends 42,760,448  (bf16)
    //  zrb    @ 42,760,448  4,000,000  ends 46,760,448  (< 256 MiB)
    char* ws = (char*)d_ws;
    int* cnt               = (int*)(ws);
    unsigned short* bucket = (unsigned short*)(ws + 262144);
    unsigned short* Wt1    = (unsigned short*)(ws + 6662144);
    unsigned short* Wt2    = (unsigned short*)(ws + 6727680);
    unsigned short* hb     = (unsigned short*)(ws + 6748160);
    unsigned char*  ylb    = (unsigned char*)(ws + 19560448);
    unsigned short* yrb    = (unsigned short*)(ws + 25960448);
    unsigned short* zlb    = (unsigned short*)(ws + 38760448);
    unsigned short* zrb    = (unsigned short*)(ws + 42760448);

    // --- prep (weight transposes + cnt zero) + bucket build (1 atomic pass)
    prep_kernel<<<KP_GRID, 256, 0, stream>>>(W1l, W1r, Wt1, W2l, W2r, Wt2, cnt);
    fill_bucket_kernel<<<EDGE_BATCH_BLOCKS, 256, 0, stream>>>(src, dst, cnt,
                                                              bucket);

    const int AGG_BLOCKS = (N_NODES + 3) / 4;

    // --- Layer 1 (x converted inline via LDS staging in gemm1; ylb fp8)
    gemm1_mfma_kernel<<<M_PAD / 64, 256, 0, stream>>>(x, Wt1, ylb, yrb);
    agg_relu1_kernel<<<AGG_BLOCKS, 256, 0, stream>>>(
        (const unsigned short*)ylb, cnt, bucket, (const float2*)b1,
        (const unsigned int*)yrb, (unsigned int*)hb);

    // --- Layer 2
    gemm2_mfma_kernel<<<M_PAD / 64, 256, 0, stream>>>(hb, Wt2, zlb, zrb);
    agg_out2_kernel<<<AGG_BLOCKS, 256, 0, stream>>>(
        zlb, zrb, cnt, bucket, b2, out);
}